// Round 10
// baseline (101.933 us; speedup 1.0000x reference)
//
#include <hip/hip_runtime.h>
#include <hip/hip_cooperative_groups.h>
#include <math.h>

namespace cg = cooperative_groups;

// N=4, M=64, A=64, O=5, F=256
// Single cooperative kernel, 256 blocks x 512 threads (all co-resident).
// Phase 1: G[n][u][b][a] (ws): 64 MLP tasks per block on lanes of wave 0.
//   u<2 -> M[u][0]+M[u][1]; u=2 -> M[2][2]   (M = 5x bilinear+swish of S)
// grid.sync()
// Phase 2 (block = nm): coup -> D -> W3 (all in LDS), then stream ao:
//   coup[b][k] = Y_k(unit(R)) * ||C[b,:]||
//   D0[b][i] = sum_k coup[b][k]*cgc[k][i][0]
//   Dz[b][i] = sum_k coup[b][k]*(cgc[k][i][1]+cgc[k][i][2]+cgc[k][i][3])
//   W3[a][u][i] = sum_b G[n][u][b][a] * (u==2 ? Dz : D0)[b][i]
//   out[nm][f][i] = sum_a  W3[a][0][i]*(C[a,0]*ao[a,0,f])
//                        + W3[a][1][i]*(C[a,1]*ao[a,1,f])
//                        + W3[a][2][i]*(C[a,2]*ao[a,2,f]+C[a,3]*ao[a,3,f]+C[a,4]*ao[a,4,f])
//
// ws layout (floats): G off 0 (49152 f)

typedef float v4f __attribute__((ext_vector_type(4)));
static __device__ inline v4f splat4(float s) { return (v4f){s, s, s, s}; }

__global__ __launch_bounds__(512) void k_fused(
        const float* __restrict__ ao, const float* __restrict__ C,
        const float* __restrict__ S, const float* __restrict__ R,
        const float* __restrict__ wst, const float* __restrict__ cgc,
        float* __restrict__ G, float* __restrict__ out) {
    __shared__ float s_coup[64 * 9];
    __shared__ float s_D[2 * 9 * 64];   // [pm][i][b]
    __shared__ float s_W3[64 * 28];     // [a][u*9+i], padded row 27->28
    __shared__ float s_C[320];

    const int blk = blockIdx.x;   // 256
    const int tid = threadIdx.x;  // 512

    // ---------- Phase 1: G ----------
    if (tid < 64) {
        const int t = blk * 64 + tid;
        const int n = t >> 12;
        const int a = (t >> 6) & 63;
        const int b = t & 63;
        float M[3][3];
#pragma unroll
        for (int x = 0; x < 3; ++x)
#pragma unroll
            for (int y = 0; y < 3; ++y)
                M[x][y] = S[(((n * 64 + a) * 3 + x) * 64 + b) * 3 + y];
#pragma unroll
        for (int it = 0; it < 5; ++it) {
            float w[3][3];
#pragma unroll
            for (int x = 0; x < 3; ++x)
#pragma unroll
                for (int y = 0; y < 3; ++y)
                    w[x][y] = wst[it * 9 + x * 3 + y];
            float T[3][3];
#pragma unroll
            for (int x = 0; x < 3; ++x)
#pragma unroll
                for (int d = 0; d < 3; ++d)
                    T[x][d] = w[x][0] * M[0][d] + w[x][1] * M[1][d] + w[x][2] * M[2][d];
#pragma unroll
            for (int x = 0; x < 3; ++x)
#pragma unroll
                for (int c = 0; c < 3; ++c) {
                    float v = T[x][0] * w[c][0] + T[x][1] * w[c][1] + T[x][2] * w[c][2];
                    M[x][c] = v / (1.f + expf(-v));   // swish
                }
        }
        const float g0 = M[0][0] + M[0][1];
        const float g1 = M[1][0] + M[1][1];
        const float gz = M[2][2];
        const size_t base = (size_t)n * 12288 + (size_t)b * 64 + a;
        G[base]        = g0;
        G[base + 4096] = g1;
        G[base + 8192] = gz;
    }
    __threadfence();
    cg::this_grid().sync();

    // ---------- Phase 2: per-nm ----------
    const int nm = blk;
    const int n = nm >> 6;

    // s_C + coup
    for (int e = tid; e < 320; e += 512) s_C[e] = C[(size_t)nm * 320 + e];
    if (tid < 64) {
        const int b = tid;
        const float* rp = R + ((size_t)nm * 64 + b) * 3;
        float x = rp[0], y = rp[1], z = rp[2];
        float rn = sqrtf(x * x + y * y + z * z) + 1e-12f;
        x /= rn; y /= rn; z /= rn;
        const float* cp = C + ((size_t)nm * 64 + b) * 5;
        float cn = 0.f;
#pragma unroll
        for (int o = 0; o < 5; ++o) cn += cp[o] * cp[o];
        cn = sqrtf(cn);
        const float c1 = 0.4886025119029199f;
        const float c2 = 1.0925484305920792f;
        float Y[9];
        Y[0] = 0.28209479177387814f;
        Y[1] = c1 * y;
        Y[2] = c1 * z;
        Y[3] = c1 * x;
        Y[4] = c2 * x * y;
        Y[5] = c2 * y * z;
        Y[6] = 0.31539156525252005f * (3.f * z * z - 1.f);
        Y[7] = c2 * x * z;
        Y[8] = 0.5462742152960396f * (x * x - y * y);
#pragma unroll
        for (int k = 0; k < 9; ++k) s_coup[b * 9 + k] = Y[k] * cn;
    }
    __syncthreads();

    // D[pm][i][b]: 576 (b,i) pairs, strided over 512 threads
    for (int e = tid; e < 576; e += 512) {
        const int b = e & 63, i = e >> 6;
        float d0 = 0.f, dz = 0.f;
#pragma unroll
        for (int k = 0; k < 9; ++k) {
            float cp = s_coup[b * 9 + k];
            const float* cg = cgc + k * 81 + i * 9;
            d0 = fmaf(cp, cg[0], d0);
            dz = fmaf(cp, cg[1] + cg[2] + cg[3], dz);
        }
        s_D[(0 * 9 + i) * 64 + b] = d0;
        s_D[(1 * 9 + i) * 64 + b] = dz;
    }
    __syncthreads();

    // W3: 9 tasks (u, i-triple) over 8 waves (wave 0 takes task 8 too)
    const int wid = __builtin_amdgcn_readfirstlane(tid >> 6);  // 0..7
    const int lane = tid & 63;   // a
    for (int pp = wid; pp < 9; pp += 8) {
        const int u = pp / 3;
        const int i0 = (pp % 3) * 3;
        const int pm = (u == 2) ? 1 : 0;
        const float* gp = G + (size_t)n * 12288 + (size_t)u * 4096 + lane;  // + b*64
        const float* dp = &s_D[(pm * 9 + i0) * 64];                          // + b
        float a0 = 0.f, a1 = 0.f, a2 = 0.f;
#pragma unroll 8
        for (int b = 0; b < 64; ++b) {
            float g = gp[b * 64];          // coalesced over lane=a
            a0 = fmaf(g, dp[b], a0);       // broadcast LDS reads
            a1 = fmaf(g, dp[64 + b], a1);
            a2 = fmaf(g, dp[128 + b], a2);
        }
        s_W3[lane * 28 + u * 9 + i0 + 0] = a0;
        s_W3[lane * 28 + u * 9 + i0 + 1] = a1;
        s_W3[lane * 28 + u * 9 + i0 + 2] = a2;
    }
    __syncthreads();

    // ---------- Stream phase (identical structure to R8 k_out) ----------
    const int w = tid >> 6;
    const int fgrp = lane & 7;
    const int agrp = lane >> 3;
    const int f0 = w * 32 + fgrp * 4;
    const float* ap = ao + (size_t)nm * 81920 + (size_t)agrp * 1280 + f0;

    v4f acc[9];
#pragma unroll
    for (int i = 0; i < 9; ++i) acc[i] = splat4(0.f);

#pragma unroll
    for (int t = 0; t < 8; ++t) {
        const int a = agrp + 8 * t;
        const float* aop = ap + t * 10240;
        v4f v0 = *(const v4f*)(aop + 0 * 256);
        v4f v1 = *(const v4f*)(aop + 1 * 256);
        v4f v2 = *(const v4f*)(aop + 2 * 256);
        v4f v3 = *(const v4f*)(aop + 3 * 256);
        v4f v4 = *(const v4f*)(aop + 4 * 256);
        const float* cc = &s_C[a * 5];
        v4f e0 = splat4(cc[0]) * v0;
        v4f e1 = splat4(cc[1]) * v1;
        v4f e2 = splat4(cc[2]) * v2 + splat4(cc[3]) * v3 + splat4(cc[4]) * v4;
        const float* w3 = &s_W3[a * 28];
#pragma unroll
        for (int i = 0; i < 9; ++i)
            acc[i] += splat4(w3[i]) * e0 + splat4(w3[9 + i]) * e1 + splat4(w3[18 + i]) * e2;
    }

    // reduce over the 8 agrp groups (lanes xor 8,16,32)
#pragma unroll
    for (int mask = 8; mask <= 32; mask <<= 1) {
#pragma unroll
        for (int i = 0; i < 9; ++i) {
#pragma unroll
            for (int j = 0; j < 4; ++j)
                acc[i][j] += __shfl_xor(acc[i][j], mask, 64);
        }
    }

    if (agrp == 0) {
        v4f buf4[9];
        float* bp = (float*)buf4;
#pragma unroll
        for (int j = 0; j < 4; ++j)
#pragma unroll
            for (int i = 0; i < 9; ++i)
                bp[j * 9 + i] = acc[i][j];
        float* op = out + (size_t)nm * 2304 + (size_t)f0 * 9;   // 16B-aligned
#pragma unroll
        for (int q = 0; q < 9; ++q)
            *(v4f*)(op + q * 4) = buf4[q];
    }
}

extern "C" void kernel_launch(void* const* d_in, const int* in_sizes, int n_in,
                              void* d_out, int out_size, void* d_ws, size_t ws_size,
                              hipStream_t stream) {
    (void)in_sizes; (void)n_in; (void)out_size; (void)ws_size;
    const float* ao  = (const float*)d_in[0];
    const float* C   = (const float*)d_in[1];
    const float* S   = (const float*)d_in[2];
    const float* R   = (const float*)d_in[3];
    const float* wst = (const float*)d_in[4];
    const float* cgc = (const float*)d_in[5];
    float* out = (float*)d_out;
    float* G = (float*)d_ws;   // 49152 floats

    void* args[] = {(void*)&ao, (void*)&C, (void*)&S, (void*)&R,
                    (void*)&wst, (void*)&cgc, (void*)&G, (void*)&out};
    hipLaunchCooperativeKernel((void*)k_fused, dim3(256), dim3(512),
                               args, 0, stream);
}

// Round 11
// 31.517 us; speedup vs baseline: 3.2342x; 3.2342x over previous
//
#include <hip/hip_runtime.h>
#include <math.h>

// N=4, M=64, A=64, O=5, F=256
// Two kernels (no grid sync):
//   k_sc: G[n][u][b][a] from 5x bilinear+swish of S  (tiny)
//   k_go: per (nm, f-half) block: coup->D->W3 in LDS, then stream ao.
// Algebra:
//   coup[b][k] = Y_k(unit(R)) * ||C[b,:]||
//   D0[b][i] = sum_k coup[b][k]*cgc[k][i][0]
//   Dz[b][i] = sum_k coup[b][k]*(cgc[k][i][1]+cgc[k][i][2]+cgc[k][i][3])
//   W3[a][u][i] = sum_b G[n][u][b][a] * (u==2 ? Dz : D0)[b][i]
//   out[nm][f][i] = sum_a  W3[a][0][i]*(C[a,0]*ao[a,0,f])
//                        + W3[a][1][i]*(C[a,1]*ao[a,1,f])
//                        + W3[a][2][i]*(C[a,2]*ao[a,2,f]+C[a,3]*ao[a,3,f]+C[a,4]*ao[a,4,f])
// ws layout (floats): G off 0 (49152 f)

typedef float v4f __attribute__((ext_vector_type(4)));
static __device__ inline v4f splat4(float s) { return (v4f){s, s, s, s}; }

__global__ void k_sc(const float* __restrict__ S, const float* __restrict__ wst,
                     float* __restrict__ G) {
    int t = blockIdx.x * 128 + threadIdx.x;   // 16384 threads over 128 blocks
    int n = t >> 12;
    int a = (t >> 6) & 63;   // row atom
    int b = t & 63;          // col atom
    float M[3][3];
#pragma unroll
    for (int x = 0; x < 3; ++x)
#pragma unroll
        for (int y = 0; y < 3; ++y)
            M[x][y] = S[(((n * 64 + a) * 3 + x) * 64 + b) * 3 + y];
#pragma unroll
    for (int it = 0; it < 5; ++it) {
        float w[3][3];
#pragma unroll
        for (int x = 0; x < 3; ++x)
#pragma unroll
            for (int y = 0; y < 3; ++y)
                w[x][y] = wst[it * 9 + x * 3 + y];
        float T[3][3];
#pragma unroll
        for (int x = 0; x < 3; ++x)
#pragma unroll
            for (int d = 0; d < 3; ++d)
                T[x][d] = w[x][0] * M[0][d] + w[x][1] * M[1][d] + w[x][2] * M[2][d];
#pragma unroll
        for (int x = 0; x < 3; ++x)
#pragma unroll
            for (int c = 0; c < 3; ++c) {
                float v = T[x][0] * w[c][0] + T[x][1] * w[c][1] + T[x][2] * w[c][2];
                M[x][c] = v / (1.f + expf(-v));   // swish
            }
    }
    float g0 = M[0][0] + M[0][1];
    float g1 = M[1][0] + M[1][1];
    float gz = M[2][2];
    size_t base = (size_t)n * 12288 + (size_t)b * 64 + a;
    G[base]          = g0;
    G[base + 4096]   = g1;
    G[base + 8192]   = gz;
}

// Block = (nm, f-half). 512 blocks x 512 threads, 2 blocks/CU.
// lane: fgrp = lane&3 -> f0 = fh*128 + w*16 + fgrp*4; agrp = lane>>2 (16 groups);
// t-loop: a = agrp + 16*t, software-pipelined (load t+1 during FMA of t).
__global__ __launch_bounds__(512, 4) void k_go(
        const float* __restrict__ ao, const float* __restrict__ C,
        const float* __restrict__ R, const float* __restrict__ cgc,
        const float* __restrict__ G, float* __restrict__ out) {
    __shared__ float s_coup[64 * 9];
    __shared__ float s_D[2 * 9 * 64];   // [pm][i][b]
    __shared__ float s_W3[64 * 28];     // [a][u*9+i], padded
    __shared__ float s_C[320];

    const int bid = blockIdx.x;
    const int nm = bid >> 1;
    const int fh = bid & 1;
    const int n = nm >> 6;
    const int tid = threadIdx.x;
    const int w = tid >> 6;
    const int lane = tid & 63;
    const int fgrp = lane & 3;
    const int agrp = lane >> 2;
    const int f0 = fh * 128 + w * 16 + fgrp * 4;
    const float* ap = ao + (size_t)nm * 81920 + (size_t)agrp * 1280 + f0;

    // ---- prefetch t=0 (5 x float4) before the W3 phases ----
    v4f cur[5];
#pragma unroll
    for (int o = 0; o < 5; ++o)
        cur[o] = *(const v4f*)(ap + o * 256);

    // ---- phase A: coup -> D -> W3 in LDS ----
    for (int e = tid; e < 320; e += 512) s_C[e] = C[(size_t)nm * 320 + e];
    if (tid < 64) {
        const int b = tid;
        const float* rp = R + ((size_t)nm * 64 + b) * 3;
        float x = rp[0], y = rp[1], z = rp[2];
        float rn = sqrtf(x * x + y * y + z * z) + 1e-12f;
        x /= rn; y /= rn; z /= rn;
        const float* cp = C + ((size_t)nm * 64 + b) * 5;
        float cn = 0.f;
#pragma unroll
        for (int o = 0; o < 5; ++o) cn += cp[o] * cp[o];
        cn = sqrtf(cn);
        const float c1 = 0.4886025119029199f;
        const float c2 = 1.0925484305920792f;
        float Y[9];
        Y[0] = 0.28209479177387814f;
        Y[1] = c1 * y;
        Y[2] = c1 * z;
        Y[3] = c1 * x;
        Y[4] = c2 * x * y;
        Y[5] = c2 * y * z;
        Y[6] = 0.31539156525252005f * (3.f * z * z - 1.f);
        Y[7] = c2 * x * z;
        Y[8] = 0.5462742152960396f * (x * x - y * y);
#pragma unroll
        for (int k = 0; k < 9; ++k) s_coup[b * 9 + k] = Y[k] * cn;
    }
    __syncthreads();

    for (int e = tid; e < 576; e += 512) {
        const int b = e & 63, i = e >> 6;
        float d0 = 0.f, dz = 0.f;
#pragma unroll
        for (int k = 0; k < 9; ++k) {
            float cp = s_coup[b * 9 + k];
            const float* cg = cgc + k * 81 + i * 9;
            d0 = fmaf(cp, cg[0], d0);
            dz = fmaf(cp, cg[1] + cg[2] + cg[3], dz);
        }
        s_D[(0 * 9 + i) * 64 + b] = d0;
        s_D[(1 * 9 + i) * 64 + b] = dz;
    }
    __syncthreads();

    // W3: 9 tasks (u, i-triple) over 8 waves (wave 0 takes task 8 too)
    for (int pp = w; pp < 9; pp += 8) {
        const int u = pp / 3;
        const int i0 = (pp % 3) * 3;
        const int pm = (u == 2) ? 1 : 0;
        const float* gp = G + (size_t)n * 12288 + (size_t)u * 4096 + lane;  // + b*64
        const float* dp = &s_D[(pm * 9 + i0) * 64];                          // + b
        float a0 = 0.f, a1 = 0.f, a2 = 0.f;
#pragma unroll 8
        for (int b = 0; b < 64; ++b) {
            float g = gp[b * 64];
            a0 = fmaf(g, dp[b], a0);
            a1 = fmaf(g, dp[64 + b], a1);
            a2 = fmaf(g, dp[128 + b], a2);
        }
        s_W3[lane * 28 + u * 9 + i0 + 0] = a0;
        s_W3[lane * 28 + u * 9 + i0 + 1] = a1;
        s_W3[lane * 28 + u * 9 + i0 + 2] = a2;
    }
    __syncthreads();

    // ---- stream phase: software-pipelined over t (a = agrp + 16*t) ----
    v4f acc[9];
#pragma unroll
    for (int i = 0; i < 9; ++i) acc[i] = splat4(0.f);

#pragma unroll
    for (int t = 0; t < 4; ++t) {
        v4f nxt[5];
        if (t < 3) {
            const float* apn = ap + (t + 1) * 20480;
#pragma unroll
            for (int o = 0; o < 5; ++o)
                nxt[o] = *(const v4f*)(apn + o * 256);
        }
        const int a = agrp + 16 * t;
        const float* cc = &s_C[a * 5];
        v4f e0 = splat4(cc[0]) * cur[0];
        v4f e1 = splat4(cc[1]) * cur[1];
        v4f e2 = splat4(cc[2]) * cur[2] + splat4(cc[3]) * cur[3] + splat4(cc[4]) * cur[4];
        const float* w3 = &s_W3[a * 28];
#pragma unroll
        for (int i = 0; i < 9; ++i)
            acc[i] += splat4(w3[i]) * e0 + splat4(w3[9 + i]) * e1 + splat4(w3[18 + i]) * e2;
        if (t < 3) {
#pragma unroll
            for (int o = 0; o < 5; ++o) cur[o] = nxt[o];
        }
    }

    // reduce over the 16 agrp groups (lanes xor 4,8,16,32)
#pragma unroll
    for (int mask = 4; mask <= 32; mask <<= 1) {
#pragma unroll
        for (int i = 0; i < 9; ++i) {
#pragma unroll
            for (int j = 0; j < 4; ++j)
                acc[i][j] += __shfl_xor(acc[i][j], mask, 64);
        }
    }

    if (agrp == 0) {
        v4f buf4[9];
        float* bp = (float*)buf4;
#pragma unroll
        for (int j = 0; j < 4; ++j)
#pragma unroll
            for (int i = 0; i < 9; ++i)
                bp[j * 9 + i] = acc[i][j];
        float* op = out + (size_t)nm * 2304 + (size_t)f0 * 9;   // 16B-aligned
#pragma unroll
        for (int q = 0; q < 9; ++q)
            *(v4f*)(op + q * 4) = buf4[q];
    }
}

extern "C" void kernel_launch(void* const* d_in, const int* in_sizes, int n_in,
                              void* d_out, int out_size, void* d_ws, size_t ws_size,
                              hipStream_t stream) {
    (void)in_sizes; (void)n_in; (void)out_size; (void)ws_size;
    const float* ao  = (const float*)d_in[0];
    const float* C   = (const float*)d_in[1];
    const float* S   = (const float*)d_in[2];
    const float* R   = (const float*)d_in[3];
    const float* wst = (const float*)d_in[4];
    const float* cgc = (const float*)d_in[5];
    float* out = (float*)d_out;
    float* G = (float*)d_ws;   // 49152 floats

    hipLaunchKernelGGL(k_sc, dim3(128), dim3(128), 0, stream, S, wst, G);
    hipLaunchKernelGGL(k_go, dim3(512), dim3(512), 0, stream,
                       ao, C, R, cgc, G, out);
}

// Round 12
// 29.168 us; speedup vs baseline: 3.4947x; 1.0805x over previous
//
#include <hip/hip_runtime.h>
#include <math.h>

// N=4, M=64, A=64, O=5, F=256
// k_sc: G[n][u][b][a] from 5x bilinear+swish of S (tiny)
// k_go (block = nm, 8 waves): coup->D->W3->K in LDS, then wave w streams rows
//   [w*40, w*40+40) with FULL-ROW loads (64 lanes x float4 = 1KB contiguous per
//   wave-instr), acc[i] += K[r][i]*v, 8-way LDS reduce, direct out write.
// Algebra:
//   coup[b][k] = Y_k(unit(R)) * ||C[b,:]||
//   D0[b][i] = sum_k coup[b][k]*cgc[k][i][0]
//   Dz[b][i] = sum_k coup[b][k]*(cgc[k][i][1]+cgc[k][i][2]+cgc[k][i][3])
//   W3[a][u][i] = sum_b G[n][u][b][a] * (u==2 ? Dz : D0)[b][i]
//   K[r=(a,o)][i] = C[a,o] * W3[a][min(o,2)][i]
//   out[nm][f][i] = sum_r K[r][i] * ao[nm][r][f]
// ws layout (floats): G off 0 (49152 f)

typedef float v4f __attribute__((ext_vector_type(4)));
static __device__ inline v4f splat4(float s) { return (v4f){s, s, s, s}; }

__global__ void k_sc(const float* __restrict__ S, const float* __restrict__ wst,
                     float* __restrict__ G) {
    int t = blockIdx.x * 128 + threadIdx.x;   // 16384 threads over 128 blocks
    int n = t >> 12;
    int a = (t >> 6) & 63;
    int b = t & 63;
    float M[3][3];
#pragma unroll
    for (int x = 0; x < 3; ++x)
#pragma unroll
        for (int y = 0; y < 3; ++y)
            M[x][y] = S[(((n * 64 + a) * 3 + x) * 64 + b) * 3 + y];
#pragma unroll
    for (int it = 0; it < 5; ++it) {
        float w[3][3];
#pragma unroll
        for (int x = 0; x < 3; ++x)
#pragma unroll
            for (int y = 0; y < 3; ++y)
                w[x][y] = wst[it * 9 + x * 3 + y];
        float T[3][3];
#pragma unroll
        for (int x = 0; x < 3; ++x)
#pragma unroll
            for (int d = 0; d < 3; ++d)
                T[x][d] = w[x][0] * M[0][d] + w[x][1] * M[1][d] + w[x][2] * M[2][d];
#pragma unroll
        for (int x = 0; x < 3; ++x)
#pragma unroll
            for (int c = 0; c < 3; ++c) {
                float v = T[x][0] * w[c][0] + T[x][1] * w[c][1] + T[x][2] * w[c][2];
                M[x][c] = v / (1.f + expf(-v));   // swish
            }
    }
    float g0 = M[0][0] + M[0][1];
    float g1 = M[1][0] + M[1][1];
    float gz = M[2][2];
    size_t base = (size_t)n * 12288 + (size_t)b * 64 + a;
    G[base]          = g0;
    G[base + 4096]   = g1;
    G[base + 8192]   = gz;
}

__global__ __launch_bounds__(512) void k_go(
        const float* __restrict__ ao, const float* __restrict__ C,
        const float* __restrict__ R, const float* __restrict__ cgc,
        const float* __restrict__ G, float* __restrict__ out) {
    __shared__ float s_coup[576];
    __shared__ float s_D[1152];          // [pm][i][b]
    __shared__ float s_W3[64 * 28];      // [a][u*9+i]
    __shared__ float s_C[320];
    __shared__ float s_K[320 * 12];      // [r][i], padded to 12 (16B-aligned rows)
    __shared__ float s_par[8 * 2368];    // [wave][lane*37 + j*9 + i], pad 36->37

    const int nm = blockIdx.x;
    const int n = nm >> 6;
    const int tid = threadIdx.x;
    const int w = tid >> 6;
    const int lane = tid & 63;

    // ---- prefetch this wave's first 4 rows (1KB contiguous per wave-load) ----
    const float* aw = ao + (size_t)nm * 81920 + (size_t)(w * 40) * 256 + lane * 4;
    v4f b0 = *(const v4f*)(aw + 0 * 256);
    v4f b1 = *(const v4f*)(aw + 1 * 256);
    v4f b2 = *(const v4f*)(aw + 2 * 256);
    v4f b3 = *(const v4f*)(aw + 3 * 256);

    // ---- phase A: coup -> D -> W3 -> K ----
    for (int e = tid; e < 320; e += 512) s_C[e] = C[(size_t)nm * 320 + e];
    if (tid < 64) {
        const int b = tid;
        const float* rp = R + ((size_t)nm * 64 + b) * 3;
        float x = rp[0], y = rp[1], z = rp[2];
        float rn = sqrtf(x * x + y * y + z * z) + 1e-12f;
        x /= rn; y /= rn; z /= rn;
        const float* cp = C + ((size_t)nm * 64 + b) * 5;
        float cn = 0.f;
#pragma unroll
        for (int o = 0; o < 5; ++o) cn += cp[o] * cp[o];
        cn = sqrtf(cn);
        const float c1 = 0.4886025119029199f;
        const float c2 = 1.0925484305920792f;
        float Y[9];
        Y[0] = 0.28209479177387814f;
        Y[1] = c1 * y;
        Y[2] = c1 * z;
        Y[3] = c1 * x;
        Y[4] = c2 * x * y;
        Y[5] = c2 * y * z;
        Y[6] = 0.31539156525252005f * (3.f * z * z - 1.f);
        Y[7] = c2 * x * z;
        Y[8] = 0.5462742152960396f * (x * x - y * y);
#pragma unroll
        for (int k = 0; k < 9; ++k) s_coup[b * 9 + k] = Y[k] * cn;
    }
    __syncthreads();

    for (int e = tid; e < 576; e += 512) {
        const int b = e & 63, i = e >> 6;
        float d0 = 0.f, dz = 0.f;
#pragma unroll
        for (int k = 0; k < 9; ++k) {
            float cp = s_coup[b * 9 + k];
            const float* cg = cgc + k * 81 + i * 9;
            d0 = fmaf(cp, cg[0], d0);
            dz = fmaf(cp, cg[1] + cg[2] + cg[3], dz);
        }
        s_D[(0 * 9 + i) * 64 + b] = d0;
        s_D[(1 * 9 + i) * 64 + b] = dz;
    }
    __syncthreads();

    for (int pp = w; pp < 9; pp += 8) {
        const int u = pp / 3;
        const int i0 = (pp % 3) * 3;
        const int pm = (u == 2) ? 1 : 0;
        const float* gp = G + (size_t)n * 12288 + (size_t)u * 4096 + lane;  // + b*64
        const float* dp = &s_D[(pm * 9 + i0) * 64];
        float a0 = 0.f, a1 = 0.f, a2 = 0.f;
#pragma unroll 8
        for (int b = 0; b < 64; ++b) {
            float g = gp[b * 64];
            a0 = fmaf(g, dp[b], a0);
            a1 = fmaf(g, dp[64 + b], a1);
            a2 = fmaf(g, dp[128 + b], a2);
        }
        s_W3[lane * 28 + u * 9 + i0 + 0] = a0;
        s_W3[lane * 28 + u * 9 + i0 + 1] = a1;
        s_W3[lane * 28 + u * 9 + i0 + 2] = a2;
    }
    __syncthreads();

    // K[r][i] = C[r] * W3[a][u][i]
    for (int e = tid; e < 2880; e += 512) {
        int r = e / 9, i = e - r * 9;
        int a = r / 5, o = r - a * 5;
        int u = o < 2 ? o : 2;
        s_K[r * 12 + i] = s_C[r] * s_W3[a * 28 + u * 9 + i];
    }
    __syncthreads();

    // ---- stream: 40 rows/wave, modulo-4 register rotation ----
    v4f acc[9];
#pragma unroll
    for (int i = 0; i < 9; ++i) acc[i] = splat4(0.f);
    const int rbase = w * 40;

#define ROW_STEP(BUF, T_OFF)                                              \
    {                                                                     \
        const float* Kp = &s_K[(rbase + 4 * tt + (T_OFF)) * 12];          \
        v4f k0 = *(const v4f*)(Kp);                                       \
        v4f k1 = *(const v4f*)(Kp + 4);                                   \
        float k8 = Kp[8];                                                 \
        acc[0] += splat4(k0.x) * BUF;                                     \
        acc[1] += splat4(k0.y) * BUF;                                     \
        acc[2] += splat4(k0.z) * BUF;                                     \
        acc[3] += splat4(k0.w) * BUF;                                     \
        acc[4] += splat4(k1.x) * BUF;                                     \
        acc[5] += splat4(k1.y) * BUF;                                     \
        acc[6] += splat4(k1.z) * BUF;                                     \
        acc[7] += splat4(k1.w) * BUF;                                     \
        acc[8] += splat4(k8) * BUF;                                       \
        if (tt < 9) BUF = *(const v4f*)(aw + (4 * tt + (T_OFF) + 4) * 256); \
    }

    for (int tt = 0; tt < 10; ++tt) {
        ROW_STEP(b0, 0)
        ROW_STEP(b1, 1)
        ROW_STEP(b2, 2)
        ROW_STEP(b3, 3)
    }
#undef ROW_STEP

    // ---- 8-way LDS reduce (pad-37: 2 lanes/bank, conflict-free) ----
    {
        float* sp = &s_par[w * 2368 + lane * 37];
#pragma unroll
        for (int j = 0; j < 4; ++j)
#pragma unroll
            for (int i = 0; i < 9; ++i)
                sp[j * 9 + i] = acc[i][j];
    }
    __syncthreads();
    for (int s = tid; s < 2304; s += 512) {
        int f = s / 9, i = s - f * 9;
        int off = (f >> 2) * 37 + (f & 3) * 9 + i;
        float sum = 0.f;
#pragma unroll
        for (int w2 = 0; w2 < 8; ++w2) sum += s_par[w2 * 2368 + off];
        out[(size_t)nm * 2304 + s] = sum;
    }
}

extern "C" void kernel_launch(void* const* d_in, const int* in_sizes, int n_in,
                              void* d_out, int out_size, void* d_ws, size_t ws_size,
                              hipStream_t stream) {
    (void)in_sizes; (void)n_in; (void)out_size; (void)ws_size;
    const float* ao  = (const float*)d_in[0];
    const float* C   = (const float*)d_in[1];
    const float* S   = (const float*)d_in[2];
    const float* R   = (const float*)d_in[3];
    const float* wst = (const float*)d_in[4];
    const float* cgc = (const float*)d_in[5];
    float* out = (float*)d_out;
    float* G = (float*)d_ws;   // 49152 floats

    hipLaunchKernelGGL(k_sc, dim3(128), dim3(128), 0, stream, S, wst, G);
    hipLaunchKernelGGL(k_go, dim3(256), dim3(512), 0, stream,
                       ao, C, R, cgc, G, out);
}